// Round 4
// baseline (342.470 us; speedup 1.0000x reference)
//
#include <hip/hip_runtime.h>
#include <cstdint>

#define BATCH 8
#define SEQ   4096
#define DIN   1024
#define DST   64
#define CHUNK 32
#define NCC   (SEQ/CHUNK)    // 128 chunks per batch
#define NBLK1 (BATCH*NCC)    // 1024 k1 blocks

typedef __attribute__((ext_vector_type(8))) short short8;
typedef __attribute__((ext_vector_type(4))) short short4v;
typedef __attribute__((ext_vector_type(4))) float f32x4;

__device__ __forceinline__ short f2bf(float f) {
    union { float f; unsigned u; } v; v.f = f;
    unsigned r = v.u + 0x7fffu + ((v.u >> 16) & 1u);   // RNE
    return (short)(r >> 16);
}
__device__ __forceinline__ float softplus_f(float x) {
    return (x > 20.f) ? x : log1pf(expf(x));
}

// ---------------- k0: precompute ----------------
__global__ void ssm_k0(const float* __restrict__ logA, const float* __restrict__ Bm,
                       const float* __restrict__ Cm, const float* __restrict__ logdelta,
                       short* __restrict__ Bb, short* __restrict__ Cb,
                       float* __restrict__ a_o, float* __restrict__ l2a_o,
                       float* __restrict__ aL_o)
{
    __shared__ float red[256];
    int blk = blockIdx.x, tid = threadIdx.x;
    if (blk < DST) {
        int n = blk;
        float An = -expf(logA[n]);
        float acc = 0.f;
        #pragma unroll
        for (int ii = 0; ii < DIN/256; ++ii) {
            int i = ii*256 + tid;
            float dlt = softplus_f(logdelta[i]);
            Bb[n*DIN + i] = f2bf(Bm[n*DIN + i] * dlt);
            acc += expf(dlt * An);
        }
        red[tid] = acc; __syncthreads();
        for (int s = 128; s > 0; s >>= 1) {
            if (tid < s) red[tid] += red[tid + s];
            __syncthreads();
        }
        if (tid == 0) {
            float a = red[0] * (1.f/DIN);
            a_o[n]   = a;
            l2a_o[n] = log2f(a);
            float p = a;
            #pragma unroll
            for (int q = 0; q < 5; ++q) p = p*p;      // a^32 = a^CHUNK
            aL_o[n] = p;
        }
    } else {
        int base = (blk - DST) * (DIN*DST/16);
        for (int e = tid; e < DIN*DST/16; e += 256)
            Cb[base + e] = f2bf(Cm[base + e]);
    }
}

// ---------------- k1: coalesced-staged Bu GEMM + chunk-local scan ----------------
// block = one (batch, 32-t chunk). u staged to LDS via lane-contiguous float4
// loads (full-line coalescing), bf16-converted; MFMA A-frags via ds_read_b128.
// 4 waves = 2 m-tiles x 2 n-halves; K accumulated over two 512-wide stages.
__global__ __launch_bounds__(256) void ssm_k1(
    const float* __restrict__ u, const short* __restrict__ Bb,
    const float* __restrict__ a_i, float* __restrict__ xloc, float* __restrict__ carry)
{
    int blk = blockIdx.x;
    int b = blk >> 7, cc = blk & (NCC-1);
    int tid = threadIdx.x;
    int w = tid >> 6, lane = tid & 63;
    int wm = w & 1, wn = w >> 1;
    int l16 = lane & 15, quad = lane >> 4;

    __shared__ short us[CHUNK][520];      // 33.3 KB (pad 8 shorts: 2-way banks)
    __shared__ float bu[CHUNK][DST+1];    // 8.3 KB

    long rowbase = ((long)b << 12) + (cc << 5);
    f32x4 acc0 = {0,0,0,0}, acc1 = {0,0,0,0};

    for (int s2 = 0; s2 < 2; ++s2) {
        #pragma unroll
        for (int it = 0; it < 16; ++it) {       // 4096 float4 / 256 thr
            int f = it*256 + tid;
            int row = f >> 7;                   // 128 float4 per 512-col row
            int c4  = f & 127;
            float4 v = *(const float4*)(u + (rowbase + row)*DIN + s2*512 + c4*4);
            short4v sv;
            sv[0]=f2bf(v.x); sv[1]=f2bf(v.y); sv[2]=f2bf(v.z); sv[3]=f2bf(v.w);
            *(short4v*)(&us[row][c4*4]) = sv;
        }
        __syncthreads();
        const short* bbn0 = Bb + (wn*32 +  0 + l16)*DIN + s2*512 + quad*8;
        const short* bbn1 = Bb + (wn*32 + 16 + l16)*DIN + s2*512 + quad*8;
        #pragma unroll 4
        for (int ks = 0; ks < 16; ++ks) {
            short8 af = *(const short8*)(&us[wm*16 + l16][ks*32 + quad*8]);
            short8 b0 = *(const short8*)(bbn0 + ks*32);
            short8 b1 = *(const short8*)(bbn1 + ks*32);
            acc0 = __builtin_amdgcn_mfma_f32_16x16x32_bf16(af, b0, acc0, 0,0,0);
            acc1 = __builtin_amdgcn_mfma_f32_16x16x32_bf16(af, b1, acc1, 0,0,0);
        }
        __syncthreads();
    }

    {   // D-layout: row axis (quad*4+r) = A(u t-row), col (l16) = B(n)
        int trow = wm*16 + (quad << 2);
        #pragma unroll
        for (int r = 0; r < 4; ++r) {
            bu[trow + r][wn*32 +  0 + l16] = acc0[r];
            bu[trow + r][wn*32 + 16 + l16] = acc1[r];
        }
    }
    __syncthreads();

    if (tid < DST) {                       // wave 0: 32-step local scan
        int n = tid;
        float an = a_i[n];
        float x = 0.f;
        float* xp = xloc + rowbase * DST + n;
        #pragma unroll
        for (int t = 0; t < CHUNK; ++t) {
            x = x * an + bu[t][n];
            xp[(long)t * DST] = x;
        }
        carry[blk * DST + n] = x;
    }
}

// ---------------- k2: Kogge-Stone cross-chunk prefix (8 blocks, ~3 us) ------
// inclusive[c] = sum_{p<=c} carry[p] * aL^(c-p); Xin[c] = inclusive[c-1], Xin[0]=0
__global__ __launch_bounds__(256) void ssm_k2(
    const float* __restrict__ carry, const float* __restrict__ aLp,
    float* __restrict__ Xin)
{
    __shared__ float v[2][NCC][DST+1];     // 66.6 KB ping-pong
    int b = blockIdx.x, tid = threadIdx.x;
    int n = tid & 63;
    for (int f = tid; f < NCC*DST; f += 256) {
        int c = f >> 6, nn = f & 63;
        v[0][c][nn] = carry[(b*NCC + c)*DST + nn];
    }
    float fd = aLp[n];
    __syncthreads();
    int pp = 0;
    for (int d = 1; d < NCC; d <<= 1) {
        #pragma unroll 4
        for (int r = 0; r < NCC/4; ++r) {
            int c = (tid >> 6) + r*4;
            float val = v[pp][c][n];
            if (c >= d) val += fd * v[pp][c-d][n];
            v[pp^1][c][n] = val;
        }
        fd *= fd;
        pp ^= 1;
        __syncthreads();
    }
    for (int f = tid; f < NCC*DST; f += 256) {
        int c = f >> 6, nn = f & 63;
        Xin[(b*NCC + c)*DST + nn] = (c == 0) ? 0.f : v[pp][c-1][nn];
    }
}

// ---------------- k3: correction + y GEMM with LDS-staged coalesced epilogue --
// block = 16 t-rows x 1024 i. Per 256-col segment: MFMA -> ybuf (LDS) -> flush
// with wave-contiguous 1KB u-loads / y-stores (+D*u fused in flush).
__global__ __launch_bounds__(256) void ssm_k3(
    const float* __restrict__ u, const float* __restrict__ xloc,
    const float* __restrict__ Xin, const float* __restrict__ l2a,
    const short* __restrict__ Cb, const float* __restrict__ Dv,
    float* __restrict__ y)
{
    int tblk = blockIdx.x;                 // 2048 blocks
    long t0 = (long)tblk << 4;
    int b = (int)(t0 >> 12);
    int tloc0 = (int)(t0 & (SEQ-1));
    int c = tloc0 >> 5;                    // 16-row tile never crosses a 32-chunk
    int jbase = tloc0 & (CHUNK-1);

    __shared__ float E_lds[DST];
    __shared__ short xs[16][72];
    __shared__ float ybuf[16][260];        // 16.6 KB, 16B-aligned rows

    int tid = threadIdx.x;
    if (tid < DST)
        E_lds[tid] = Xin[(b*NCC + c)*DST + tid];
    __syncthreads();

    {
        int m  = tid >> 4;
        int n0 = (tid & 15) * 4;
        long t = t0 + m;
        int j  = jbase + m;
        float4 xv = *(const float4*)(xloc + t*DST + n0);
        float4 la = *(const float4*)(l2a + n0);
        float4 Ev = *(const float4*)(&E_lds[n0]);
        float jp = (float)(j + 1);
        short4v xsv;
        xsv[0] = f2bf(xv.x + exp2f(jp*la.x)*Ev.x);
        xsv[1] = f2bf(xv.y + exp2f(jp*la.y)*Ev.y);
        xsv[2] = f2bf(xv.z + exp2f(jp*la.z)*Ev.z);
        xsv[3] = f2bf(xv.w + exp2f(jp*la.w)*Ev.w);
        *(short4v*)(&xs[m][n0]) = xsv;
    }
    __syncthreads();

    int w = tid >> 6, lane = tid & 63;
    int l16 = lane & 15, quad = lane >> 4;

    // B-operand: x fragment (col = t = l16, k = quad*8 + j)
    short8 x0 = *(const short8*)(&xs[l16][ 0 + quad*8]);
    short8 x1 = *(const short8*)(&xs[l16][32 + quad*8]);

    for (int s = 0; s < 4; ++s) {
        #pragma unroll
        for (int ii = 0; ii < 4; ++ii) {
            int i0 = s*256 + w*64 + ii*16;
            const short* cb = Cb + (long)(i0 + l16)*DST + quad*8;
            short8 c0 = *(const short8*)(cb);
            short8 c1 = *(const short8*)(cb + 32);
            f32x4 acc = {0,0,0,0};
            acc = __builtin_amdgcn_mfma_f32_16x16x32_bf16(c0, x0, acc, 0,0,0);
            acc = __builtin_amdgcn_mfma_f32_16x16x32_bf16(c1, x1, acc, 0,0,0);
            // lane holds i = i0 + quad*4 + r (rows of first operand), t = t0 + l16
            *(f32x4*)(&ybuf[l16][w*64 + ii*16 + (quad << 2)]) = acc;
        }
        __syncthreads();
        #pragma unroll
        for (int k = 0; k < 4; ++k) {      // flush: wave-contiguous rows
            int f4 = k*256 + tid;
            int row = f4 >> 6, c4 = f4 & 63;
            int col = c4 * 4;
            int gcol = s*256 + col;
            long t = t0 + row;
            float4 yv = *(const float4*)(&ybuf[row][col]);
            float4 uu = *(const float4*)(u + t*DIN + gcol);
            float4 dd = *(const float4*)(Dv + gcol);
            float4 o;
            o.x = yv.x + dd.x*uu.x;
            o.y = yv.y + dd.y*uu.y;
            o.z = yv.z + dd.z*uu.z;
            o.w = yv.w + dd.w*uu.w;
            *(float4*)(y + t*DIN + gcol) = o;
        }
        __syncthreads();
    }
}

extern "C" void kernel_launch(void* const* d_in, const int* in_sizes, int n_in,
                              void* d_out, int out_size, void* d_ws, size_t ws_size,
                              hipStream_t stream)
{
    const float* u        = (const float*)d_in[0];
    const float* logA     = (const float*)d_in[1];
    const float* Bm       = (const float*)d_in[2];
    const float* Cm       = (const float*)d_in[3];
    const float* D        = (const float*)d_in[4];
    const float* logdelta = (const float*)d_in[5];
    float* y = (float*)d_out;

    char* ws = (char*)d_ws;
    float* xloc  = (float*)(ws);                             // 8 MiB
    float* carry = (float*)(ws + 8u*1024*1024);              // 256 KiB
    float* Xin   = (float*)(ws + 8u*1024*1024 + 256*1024);   // 256 KiB
    short* Bb    = (short*)(ws + 8u*1024*1024 + 512*1024);   // 128 KiB bf16 B_bar
    short* Cb    = (short*)(ws + 8u*1024*1024 + 640*1024);   // 128 KiB bf16 C
    float* a_o   = (float*)(ws + 8u*1024*1024 + 768*1024);
    float* l2a_o = a_o + 64;
    float* aL_o  = a_o + 128;

    hipLaunchKernelGGL(ssm_k0, dim3(DST + 16), dim3(256), 0, stream,
                       logA, Bm, Cm, logdelta, Bb, Cb, a_o, l2a_o, aL_o);
    hipLaunchKernelGGL(ssm_k1, dim3(NBLK1), dim3(256), 0, stream,
                       u, Bb, a_o, xloc, carry);
    hipLaunchKernelGGL(ssm_k2, dim3(BATCH), dim3(256), 0, stream,
                       carry, aL_o, Xin);
    hipLaunchKernelGGL(ssm_k3, dim3((BATCH*SEQ)/16), dim3(256), 0, stream,
                       u, xloc, Xin, l2a_o, Cb, D, y);
}

// Round 6
// 316.671 us; speedup vs baseline: 1.0815x; 1.0815x over previous
//
#include <hip/hip_runtime.h>
#include <cstdint>

#define BATCH 8
#define SEQ   4096
#define DIN   1024
#define DST   64
#define CHUNK 32
#define NCC   (SEQ/CHUNK)    // 128 chunks per batch
#define NBLK1 (BATCH*NCC)    // 1024 k1 blocks

typedef __attribute__((ext_vector_type(8))) short short8;
typedef __attribute__((ext_vector_type(4))) short short4v;
typedef __attribute__((ext_vector_type(4))) float f32x4;

__device__ __forceinline__ short f2bf(float f) {
    union { float f; unsigned u; } v; v.f = f;
    unsigned r = v.u + 0x7fffu + ((v.u >> 16) & 1u);   // RNE
    return (short)(r >> 16);
}
__device__ __forceinline__ float softplus_f(float x) {
    return (x > 20.f) ? x : log1pf(expf(x));
}

// ---------------- k0: precompute ----------------
// blocks 0..63: row n of B_bar (bf16) + reduction a[n] = mean_i exp(delta_i * A_n)
// blocks 64..79: convert C (f32 [1024][64]) -> bf16 same layout
__global__ void ssm_k0(const float* __restrict__ logA, const float* __restrict__ Bm,
                       const float* __restrict__ Cm, const float* __restrict__ logdelta,
                       short* __restrict__ Bb, short* __restrict__ Cb,
                       float* __restrict__ a_o, float* __restrict__ l2a_o,
                       float* __restrict__ aL_o)
{
    __shared__ float red[256];
    int blk = blockIdx.x, tid = threadIdx.x;
    if (blk < DST) {
        int n = blk;
        float An = -expf(logA[n]);
        float acc = 0.f;
        #pragma unroll
        for (int ii = 0; ii < DIN/256; ++ii) {
            int i = ii*256 + tid;
            float dlt = softplus_f(logdelta[i]);
            Bb[n*DIN + i] = f2bf(Bm[n*DIN + i] * dlt);
            acc += expf(dlt * An);
        }
        red[tid] = acc; __syncthreads();
        for (int s = 128; s > 0; s >>= 1) {
            if (tid < s) red[tid] += red[tid + s];
            __syncthreads();
        }
        if (tid == 0) {
            float a = red[0] * (1.f/DIN);
            a_o[n]   = a;
            l2a_o[n] = log2f(a);
            float p = a;
            #pragma unroll
            for (int q = 0; q < 5; ++q) p = p*p;      // a^32 = a^CHUNK
            aL_o[n] = p;
        }
    } else {
        int base = (blk - DST) * (DIN*DST/16);
        for (int e = tid; e < DIN*DST/16; e += 256)
            Cb[base + e] = f2bf(Cm[base + e]);
    }
}

// ---------------- k1: register-direct Bu GEMM + chunk-local scan ----------------
// block = one (batch, 32-t chunk). 4 waves: wr = m-tile (2), wk = K-half (2).
// No barriers in the K-loop (register streaming) — r3 structure, proven faster
// than the LDS-staged variant (r4: 96 us, 3 blk/CU, phase-serialized).
__global__ __launch_bounds__(256) void ssm_k1(
    const float* __restrict__ u, const short* __restrict__ Bb,
    const float* __restrict__ a_i, float* __restrict__ xloc, float* __restrict__ carry)
{
    int blk = blockIdx.x;                 // b*NCC + cc
    int b = blk >> 7, cc = blk & (NCC-1);
    int tid = threadIdx.x;
    int w = tid >> 6, lane = tid & 63;
    int wr = w & 1, wk = w >> 1;
    int m = lane & 15, quad = lane >> 4;

    long row = ((long)b << 12) + (cc << 5) + (wr << 4) + m;   // global bt row
    const float* up  = u  + row * DIN + wk*(DIN/2) + quad * 8;
    const short* bb0 = Bb + wk*(DIN/2) + quad * 8;

    f32x4 acc0 = {0,0,0,0}, acc1 = {0,0,0,0}, acc2 = {0,0,0,0}, acc3 = {0,0,0,0};

    #pragma unroll 4
    for (int ks = 0; ks < DIN/64; ++ks) {     // 16 iters of K=32 within this half
        const float4* uv = (const float4*)(up + ks*32);
        float4 ua = uv[0];
        float4 ub = uv[1];
        short8 af;
        af[0]=f2bf(ua.x); af[1]=f2bf(ua.y); af[2]=f2bf(ua.z); af[3]=f2bf(ua.w);
        af[4]=f2bf(ub.x); af[5]=f2bf(ub.y); af[6]=f2bf(ub.z); af[7]=f2bf(ub.w);
        const short* bbase = bb0 + ks*32;
        short8 b0 = *(const short8*)(bbase + ( 0 + m)*DIN);
        short8 b1 = *(const short8*)(bbase + (16 + m)*DIN);
        short8 b2 = *(const short8*)(bbase + (32 + m)*DIN);
        short8 b3 = *(const short8*)(bbase + (48 + m)*DIN);
        acc0 = __builtin_amdgcn_mfma_f32_16x16x32_bf16(af, b0, acc0, 0,0,0);
        acc1 = __builtin_amdgcn_mfma_f32_16x16x32_bf16(af, b1, acc1, 0,0,0);
        acc2 = __builtin_amdgcn_mfma_f32_16x16x32_bf16(af, b2, acc2, 0,0,0);
        acc3 = __builtin_amdgcn_mfma_f32_16x16x32_bf16(af, b3, acc3, 0,0,0);
    }

    __shared__ float bu[2][CHUNK][DST+4];     // +4 pad: store conflicts 4-way -> 2-way (free)
    int trow = (wr << 4) + (quad << 2);
    #pragma unroll
    for (int r = 0; r < 4; ++r) {
        bu[wk][trow + r][ 0 + m] = acc0[r];
        bu[wk][trow + r][16 + m] = acc1[r];
        bu[wk][trow + r][32 + m] = acc2[r];
        bu[wk][trow + r][48 + m] = acc3[r];
    }
    __syncthreads();

    if (tid < DST) {                       // wave 0: 32-step local scan
        int n = tid;
        float an = a_i[n];
        float x = 0.f;
        float* xp = xloc + (((long)b << 12) + (cc << 5)) * DST + n;
        #pragma unroll
        for (int t = 0; t < CHUNK; ++t) {
            x = x * an + (bu[0][t][n] + bu[1][t][n]);
            xp[(long)t * DST] = x;
        }
        carry[blk * DST + n] = x;
    }
}

// ---------------- k3: inline prefix + correction + y GEMM, staged epilogue ----
// block = 16 t-rows x 1024 i. E computed in-block (Horner over L2-resident
// carries). Per 256-col segment: MFMA -> ybuf (LDS) -> flush with
// wave-contiguous 1KB u-loads and NON-TEMPORAL y-stores (keep u in L3).
__global__ __launch_bounds__(256) void ssm_k3(
    const float* __restrict__ u, const float* __restrict__ xloc,
    const float* __restrict__ carry, const float* __restrict__ aLp,
    const float* __restrict__ l2a, const short* __restrict__ Cb,
    const float* __restrict__ Dv, float* __restrict__ y)
{
    int tblk = blockIdx.x;                 // 2048 blocks
    long t0 = (long)tblk << 4;
    int b = (int)(t0 >> 12);
    int tloc0 = (int)(t0 & (SEQ-1));
    int c = tloc0 >> 5;                    // 16-row tile never crosses a 32-chunk
    int jbase = tloc0 & (CHUNK-1);

    __shared__ float E_lds[DST];
    __shared__ short xs[16][72];
    __shared__ float ybuf[16][260];        // 16.6 KB, 16B-aligned rows

    int tid = threadIdx.x;
    if (tid < DST) {                       // Horner prefix over carries of chunks < c
        int n = tid;
        float al = aLp[n];
        float E = 0.f;
        const float* cp = carry + (b*NCC)*DST + n;
        for (int p = 0; p < c; ++p)
            E = E * al + cp[p*DST];
        E_lds[n] = E;
    }
    __syncthreads();

    {
        int m  = tid >> 4;
        int n0 = (tid & 15) * 4;
        long t = t0 + m;
        int j  = jbase + m;
        float4 xv = *(const float4*)(xloc + t*DST + n0);
        float4 la = *(const float4*)(l2a + n0);
        float4 Ev = *(const float4*)(&E_lds[n0]);
        float jp = (float)(j + 1);
        short4v xsv;
        xsv[0] = f2bf(xv.x + exp2f(jp*la.x)*Ev.x);
        xsv[1] = f2bf(xv.y + exp2f(jp*la.y)*Ev.y);
        xsv[2] = f2bf(xv.z + exp2f(jp*la.z)*Ev.z);
        xsv[3] = f2bf(xv.w + exp2f(jp*la.w)*Ev.w);
        *(short4v*)(&xs[m][n0]) = xsv;
    }
    __syncthreads();

    int w = tid >> 6, lane = tid & 63;
    int l16 = lane & 15, quad = lane >> 4;

    // B-operand: x fragment (col = t = l16, k = quad*8 + j)
    short8 x0 = *(const short8*)(&xs[l16][ 0 + quad*8]);
    short8 x1 = *(const short8*)(&xs[l16][32 + quad*8]);

    for (int s = 0; s < 4; ++s) {
        #pragma unroll
        for (int ii = 0; ii < 4; ++ii) {
            int i0 = s*256 + w*64 + ii*16;
            const short* cb = Cb + (long)(i0 + l16)*DST + quad*8;
            short8 c0 = *(const short8*)(cb);
            short8 c1 = *(const short8*)(cb + 32);
            f32x4 acc = {0,0,0,0};
            acc = __builtin_amdgcn_mfma_f32_16x16x32_bf16(c0, x0, acc, 0,0,0);
            acc = __builtin_amdgcn_mfma_f32_16x16x32_bf16(c1, x1, acc, 0,0,0);
            // lane holds i = i0 + quad*4 + r (rows of first operand), t = t0 + l16
            *(f32x4*)(&ybuf[l16][w*64 + ii*16 + (quad << 2)]) = acc;
        }
        __syncthreads();
        #pragma unroll
        for (int k = 0; k < 4; ++k) {      // flush: wave-contiguous rows
            int f4 = k*256 + tid;
            int row = f4 >> 6, c4 = f4 & 63;
            int col = c4 * 4;
            int gcol = s*256 + col;
            long t = t0 + row;
            f32x4 yv = *(const f32x4*)(&ybuf[row][col]);
            const f32x4 uu = *(const f32x4*)(u + t*DIN + gcol);
            const f32x4 dd = *(const f32x4*)(Dv + gcol);
            f32x4 o;
            o.x = yv.x + dd.x*uu.x;
            o.y = yv.y + dd.y*uu.y;
            o.z = yv.z + dd.z*uu.z;
            o.w = yv.w + dd.w*uu.w;
            __builtin_nontemporal_store(o, (f32x4*)(y + t*DIN + gcol));
        }
        __syncthreads();
    }
}

extern "C" void kernel_launch(void* const* d_in, const int* in_sizes, int n_in,
                              void* d_out, int out_size, void* d_ws, size_t ws_size,
                              hipStream_t stream)
{
    const float* u        = (const float*)d_in[0];
    const float* logA     = (const float*)d_in[1];
    const float* Bm       = (const float*)d_in[2];
    const float* Cm       = (const float*)d_in[3];
    const float* D        = (const float*)d_in[4];
    const float* logdelta = (const float*)d_in[5];
    float* y = (float*)d_out;

    char* ws = (char*)d_ws;
    float* xloc  = (float*)(ws);                             // 8 MiB
    float* carry = (float*)(ws + 8u*1024*1024);              // 256 KiB
    short* Bb    = (short*)(ws + 8u*1024*1024 + 256*1024);   // 128 KiB bf16 B_bar
    short* Cb    = (short*)(ws + 8u*1024*1024 + 384*1024);   // 128 KiB bf16 C
    float* a_o   = (float*)(ws + 8u*1024*1024 + 512*1024);
    float* l2a_o = a_o + 64;
    float* aL_o  = a_o + 128;

    hipLaunchKernelGGL(ssm_k0, dim3(DST + 16), dim3(256), 0, stream,
                       logA, Bm, Cm, logdelta, Bb, Cb, a_o, l2a_o, aL_o);
    hipLaunchKernelGGL(ssm_k1, dim3(NBLK1), dim3(256), 0, stream,
                       u, Bb, a_o, xloc, carry);
    hipLaunchKernelGGL(ssm_k3, dim3((BATCH*SEQ)/16), dim3(256), 0, stream,
                       u, xloc, carry, aL_o, l2a_o, Cb, D, y);
}

// Round 8
// 309.299 us; speedup vs baseline: 1.1072x; 1.0238x over previous
//
#include <hip/hip_runtime.h>
#include <cstdint>

#define BATCH 8
#define SEQ   4096
#define DIN   1024
#define DST   64
#define CHUNK 32
#define NCC   (SEQ/CHUNK)    // 128 chunks per batch
#define NBLK1 (BATCH*NCC)    // 1024 k1 blocks

typedef __attribute__((ext_vector_type(8))) short short8;
typedef __attribute__((ext_vector_type(4))) short short4v;
typedef __attribute__((ext_vector_type(4))) float f32x4;

__device__ __forceinline__ short f2bf(float f) {
    union { float f; unsigned u; } v; v.f = f;
    unsigned r = v.u + 0x7fffu + ((v.u >> 16) & 1u);   // RNE
    return (short)(r >> 16);
}
__device__ __forceinline__ float softplus_f(float x) {
    return (x > 20.f) ? x : log1pf(expf(x));
}

// ---------------- k0: precompute ----------------
__global__ void ssm_k0(const float* __restrict__ logA, const float* __restrict__ Bm,
                       const float* __restrict__ Cm, const float* __restrict__ logdelta,
                       short* __restrict__ Bb, short* __restrict__ Cb,
                       float* __restrict__ a_o, float* __restrict__ l2a_o,
                       float* __restrict__ aL_o)
{
    __shared__ float red[256];
    int blk = blockIdx.x, tid = threadIdx.x;
    if (blk < DST) {
        int n = blk;
        float An = -expf(logA[n]);
        float acc = 0.f;
        #pragma unroll
        for (int ii = 0; ii < DIN/256; ++ii) {
            int i = ii*256 + tid;
            float dlt = softplus_f(logdelta[i]);
            Bb[n*DIN + i] = f2bf(Bm[n*DIN + i] * dlt);
            acc += expf(dlt * An);
        }
        red[tid] = acc; __syncthreads();
        for (int s = 128; s > 0; s >>= 1) {
            if (tid < s) red[tid] += red[tid + s];
            __syncthreads();
        }
        if (tid == 0) {
            float a = red[0] * (1.f/DIN);
            a_o[n]   = a;
            l2a_o[n] = log2f(a);
            float p = a;
            #pragma unroll
            for (int q = 0; q < 5; ++q) p = p*p;      // a^32 = a^CHUNK
            aL_o[n] = p;
        }
    } else {
        int base = (blk - DST) * (DIN*DST/16);
        for (int e = tid; e < DIN*DST/16; e += 256)
            Cb[base + e] = f2bf(Cm[base + e]);
    }
}

// ---------------- k1: register-direct Bu GEMM + chunk-local scan ----------------
// r3/r6 structure (proven); unroll widened 4->8 for more loads in flight.
__global__ __launch_bounds__(256) void ssm_k1(
    const float* __restrict__ u, const short* __restrict__ Bb,
    const float* __restrict__ a_i, float* __restrict__ xloc, float* __restrict__ carry)
{
    int blk = blockIdx.x;                 // b*NCC + cc
    int b = blk >> 7, cc = blk & (NCC-1);
    int tid = threadIdx.x;
    int w = tid >> 6, lane = tid & 63;
    int wr = w & 1, wk = w >> 1;
    int m = lane & 15, quad = lane >> 4;

    long row = ((long)b << 12) + (cc << 5) + (wr << 4) + m;   // global bt row
    const float* up  = u  + row * DIN + wk*(DIN/2) + quad * 8;
    const short* bb0 = Bb + wk*(DIN/2) + quad * 8;

    f32x4 acc0 = {0,0,0,0}, acc1 = {0,0,0,0}, acc2 = {0,0,0,0}, acc3 = {0,0,0,0};

    #pragma unroll 8
    for (int ks = 0; ks < DIN/64; ++ks) {     // 16 iters of K=32 within this half
        const float4* uv = (const float4*)(up + ks*32);
        float4 ua = uv[0];
        float4 ub = uv[1];
        short8 af;
        af[0]=f2bf(ua.x); af[1]=f2bf(ua.y); af[2]=f2bf(ua.z); af[3]=f2bf(ua.w);
        af[4]=f2bf(ub.x); af[5]=f2bf(ub.y); af[6]=f2bf(ub.z); af[7]=f2bf(ub.w);
        const short* bbase = bb0 + ks*32;
        short8 b0 = *(const short8*)(bbase + ( 0 + m)*DIN);
        short8 b1 = *(const short8*)(bbase + (16 + m)*DIN);
        short8 b2 = *(const short8*)(bbase + (32 + m)*DIN);
        short8 b3 = *(const short8*)(bbase + (48 + m)*DIN);
        acc0 = __builtin_amdgcn_mfma_f32_16x16x32_bf16(af, b0, acc0, 0,0,0);
        acc1 = __builtin_amdgcn_mfma_f32_16x16x32_bf16(af, b1, acc1, 0,0,0);
        acc2 = __builtin_amdgcn_mfma_f32_16x16x32_bf16(af, b2, acc2, 0,0,0);
        acc3 = __builtin_amdgcn_mfma_f32_16x16x32_bf16(af, b3, acc3, 0,0,0);
    }

    __shared__ float bu[2][CHUNK][DST+4];     // +4 pad: store conflicts 4-way -> 2-way (free)
    int trow = (wr << 4) + (quad << 2);
    #pragma unroll
    for (int r = 0; r < 4; ++r) {
        bu[wk][trow + r][ 0 + m] = acc0[r];
        bu[wk][trow + r][16 + m] = acc1[r];
        bu[wk][trow + r][32 + m] = acc2[r];
        bu[wk][trow + r][48 + m] = acc3[r];
    }
    __syncthreads();

    if (tid < DST) {                       // wave 0: 32-step local scan
        int n = tid;
        float an = a_i[n];
        float x = 0.f;
        #pragma unroll
        for (int t = 0; t < CHUNK; ++t) {
            x = x * an + (bu[0][t][n] + bu[1][t][n]);
            xp_store:
            xloc[(((long)b << 12) + (cc << 5) + t) * DST + n] = x;
        }
        carry[blk * DST + n] = x;
    }
}

// ---------------- k2: Kogge-Stone cross-chunk prefix (8 blocks, ~4 us) ------
// inclusive[c] = sum_{p<=c} carry[p] * aL^(c-p); Xin[c] = inclusive[c-1], Xin[0]=0
__global__ __launch_bounds__(256) void ssm_k2(
    const float* __restrict__ carry, const float* __restrict__ aLp,
    float* __restrict__ Xin)
{
    __shared__ float v[2][NCC][DST+1];     // 66.6 KB ping-pong
    int b = blockIdx.x, tid = threadIdx.x;
    int n = tid & 63;
    for (int f = tid; f < NCC*DST; f += 256) {
        int c = f >> 6, nn = f & 63;
        v[0][c][nn] = carry[(b*NCC + c)*DST + nn];
    }
    float fd = aLp[n];
    __syncthreads();
    int pp = 0;
    for (int d = 1; d < NCC; d <<= 1) {
        #pragma unroll 4
        for (int r = 0; r < NCC/4; ++r) {
            int c = (tid >> 6) + r*4;
            float val = v[pp][c][n];
            if (c >= d) val += fd * v[pp][c-d][n];
            v[pp^1][c][n] = val;
        }
        fd *= fd;
        pp ^= 1;
        __syncthreads();
    }
    for (int f = tid; f < NCC*DST; f += 256) {
        int c = f >> 6, nn = f & 63;
        Xin[(b*NCC + c)*DST + nn] = (c == 0) ? 0.f : v[pp][c-1][nn];
    }
}

// ---------------- k3: correction + y GEMM, staged coalesced epilogue ----
// E loaded directly from Xin (no serial Horner — that was the 2.4 TB/s stall).
__global__ __launch_bounds__(256) void ssm_k3(
    const float* __restrict__ u, const float* __restrict__ xloc,
    const float* __restrict__ Xin, const float* __restrict__ l2a,
    const short* __restrict__ Cb, const float* __restrict__ Dv,
    float* __restrict__ y)
{
    int tblk = blockIdx.x;                 // 2048 blocks
    long t0 = (long)tblk << 4;
    int b = (int)(t0 >> 12);
    int tloc0 = (int)(t0 & (SEQ-1));
    int c = tloc0 >> 5;                    // 16-row tile never crosses a 32-chunk
    int jbase = tloc0 & (CHUNK-1);

    __shared__ float E_lds[DST];
    __shared__ short xs[16][72];
    __shared__ float ybuf[16][260];        // 16.6 KB, 16B-aligned rows

    int tid = threadIdx.x;
    if (tid < DST)
        E_lds[tid] = Xin[(b*NCC + c)*DST + tid];
    __syncthreads();

    {
        int m  = tid >> 4;
        int n0 = (tid & 15) * 4;
        long t = t0 + m;
        int j  = jbase + m;
        float4 xv = *(const float4*)(xloc + t*DST + n0);
        float4 la = *(const float4*)(l2a + n0);
        float4 Ev = *(const float4*)(&E_lds[n0]);
        float jp = (float)(j + 1);
        short4v xsv;
        xsv[0] = f2bf(xv.x + exp2f(jp*la.x)*Ev.x);
        xsv[1] = f2bf(xv.y + exp2f(jp*la.y)*Ev.y);
        xsv[2] = f2bf(xv.z + exp2f(jp*la.z)*Ev.z);
        xsv[3] = f2bf(xv.w + exp2f(jp*la.w)*Ev.w);
        *(short4v*)(&xs[m][n0]) = xsv;
    }
    __syncthreads();

    int w = tid >> 6, lane = tid & 63;
    int l16 = lane & 15, quad = lane >> 4;

    // B-operand: x fragment (col = t = l16, k = quad*8 + j)
    short8 x0 = *(const short8*)(&xs[l16][ 0 + quad*8]);
    short8 x1 = *(const short8*)(&xs[l16][32 + quad*8]);

    for (int s = 0; s < 4; ++s) {
        #pragma unroll
        for (int ii = 0; ii < 4; ++ii) {
            int i0 = s*256 + w*64 + ii*16;
            const short* cb = Cb + (long)(i0 + l16)*DST + quad*8;
            short8 c0 = *(const short8*)(cb);
            short8 c1 = *(const short8*)(cb + 32);
            f32x4 acc = {0,0,0,0};
            acc = __builtin_amdgcn_mfma_f32_16x16x32_bf16(c0, x0, acc, 0,0,0);
            acc = __builtin_amdgcn_mfma_f32_16x16x32_bf16(c1, x1, acc, 0,0,0);
            // lane holds i = i0 + quad*4 + r (rows of first operand), t = t0 + l16
            *(f32x4*)(&ybuf[l16][w*64 + ii*16 + (quad << 2)]) = acc;
        }
        __syncthreads();
        #pragma unroll
        for (int k = 0; k < 4; ++k) {      // flush: wave-contiguous rows
            int f4 = k*256 + tid;
            int row = f4 >> 6, c4 = f4 & 63;
            int col = c4 * 4;
            int gcol = s*256 + col;
            long t = t0 + row;
            f32x4 yv = *(const f32x4*)(&ybuf[row][col]);
            const f32x4 uu = *(const f32x4*)(u + t*DIN + gcol);
            const f32x4 dd = *(const f32x4*)(Dv + gcol);
            f32x4 o;
            o.x = yv.x + dd.x*uu.x;
            o.y = yv.y + dd.y*uu.y;
            o.z = yv.z + dd.z*uu.z;
            o.w = yv.w + dd.w*uu.w;
            *(f32x4*)(y + t*DIN + gcol) = o;
        }
        __syncthreads();
    }
}

extern "C" void kernel_launch(void* const* d_in, const int* in_sizes, int n_in,
                              void* d_out, int out_size, void* d_ws, size_t ws_size,
                              hipStream_t stream)
{
    const float* u        = (const float*)d_in[0];
    const float* logA     = (const float*)d_in[1];
    const float* Bm       = (const float*)d_in[2];
    const float* Cm       = (const float*)d_in[3];
    const float* D        = (const float*)d_in[4];
    const float* logdelta = (const float*)d_in[5];
    float* y = (float*)d_out;

    char* ws = (char*)d_ws;
    float* xloc  = (float*)(ws);                             // 8 MiB
    float* carry = (float*)(ws + 8u*1024*1024);              // 256 KiB
    float* Xin   = (float*)(ws + 8u*1024*1024 + 256*1024);   // 256 KiB
    short* Bb    = (short*)(ws + 8u*1024*1024 + 512*1024);   // 128 KiB bf16 B_bar
    short* Cb    = (short*)(ws + 8u*1024*1024 + 640*1024);   // 128 KiB bf16 C
    float* a_o   = (float*)(ws + 8u*1024*1024 + 768*1024);
    float* l2a_o = a_o + 64;
    float* aL_o  = a_o + 128;

    hipLaunchKernelGGL(ssm_k0, dim3(DST + 16), dim3(256), 0, stream,
                       logA, Bm, Cm, logdelta, Bb, Cb, a_o, l2a_o, aL_o);
    hipLaunchKernelGGL(ssm_k1, dim3(NBLK1), dim3(256), 0, stream,
                       u, Bb, a_o, xloc, carry);
    hipLaunchKernelGGL(ssm_k2, dim3(BATCH), dim3(256), 0, stream,
                       carry, aL_o, Xin);
    hipLaunchKernelGGL(ssm_k3, dim3((BATCH*SEQ)/16), dim3(256), 0, stream,
                       u, xloc, Xin, l2a_o, Cb, D, y);
}